// Round 7
// baseline (72.650 us; speedup 1.0000x reference)
//
#include <hip/hip_runtime.h>
#include <hip/hip_bf16.h>
#include <stdint.h>

// Problem constants (from reference)
#define BATCH 4096
#define D_X   1024
#define D_Y   512

constexpr float SIGMA_INV = 0.1f;    // 1/10.0
constexpr float EPS_THR   = 46.0f;

constexpr int XSLOTS = D_X / 8;      // 128 16B-slots (8 bf16) per x row
constexpr int YSLOTS = D_Y / 8;      // 64 slots per y row

// ---- fast-path tiling: 64x64 triangular tiles -> 2080 blocks (8.1/CU) ----
constexpr int BM2   = 64;
constexpr int NT2   = BATCH / BM2;           // 64 tile-rows
constexpr int NBLK2 = NT2 * (NT2 + 1) / 2;   // 2080  (2080 % 8 == 0)
constexpr int NS2X  = D_X / 64;              // 16 X K-steps (BK=64)
constexpr int NS2Y  = D_Y / 64;              // 8  Y K-steps

// ---- fallback tiling (128^2, round-2 structure) ----
constexpr int BM = 128;
constexpr int NT = BATCH / BM;
constexpr int NBLK = NT * (NT + 1) / 2;

typedef __bf16 bf16x8 __attribute__((ext_vector_type(8)));
typedef float  f32x4  __attribute__((ext_vector_type(4)));
typedef unsigned short u16x8 __attribute__((ext_vector_type(8)));

__device__ __forceinline__ unsigned short f32_to_bf16_bits(float f) {
    unsigned int u = __builtin_bit_cast(unsigned int, f);
    unsigned int r = (u + 0x7FFFu + ((u >> 16) & 1u)) >> 16;  // RNE
    return (unsigned short)r;
}

// ===========================================================================
// Kernel 1: f32 -> bf16 (LINEAR slot layout) + row norms.
// ===========================================================================
__global__ void __launch_bounds__(192)
convert_kernel(const float* __restrict__ x, const float* __restrict__ y,
               u16x8* __restrict__ xb, u16x8* __restrict__ yb,
               float* __restrict__ sqx, float* __restrict__ sqy) {
    __shared__ float part[2];
    const int row = blockIdx.x;
    const int t   = threadIdx.x;
    const int lane = t & 63;
    const int wid  = t >> 6;

    float ss = 0.f;
    if (t < 128) {
        const float4* p = (const float4*)(x + (size_t)row * D_X + t * 8);
        float4 a = p[0], b = p[1];
        ss = a.x*a.x + a.y*a.y + a.z*a.z + a.w*a.w
           + b.x*b.x + b.y*b.y + b.z*b.z + b.w*b.w;
        u16x8 v;
        v[0] = f32_to_bf16_bits(a.x); v[1] = f32_to_bf16_bits(a.y);
        v[2] = f32_to_bf16_bits(a.z); v[3] = f32_to_bf16_bits(a.w);
        v[4] = f32_to_bf16_bits(b.x); v[5] = f32_to_bf16_bits(b.y);
        v[6] = f32_to_bf16_bits(b.z); v[7] = f32_to_bf16_bits(b.w);
        xb[(size_t)row * XSLOTS + t] = v;
    } else {
        int o = t - 128;  // 0..63
        const float4* p = (const float4*)(y + (size_t)row * D_Y + o * 8);
        float4 a = p[0], b = p[1];
        ss = a.x*a.x + a.y*a.y + a.z*a.z + a.w*a.w
           + b.x*b.x + b.y*b.y + b.z*b.z + b.w*b.w;
        u16x8 v;
        v[0] = f32_to_bf16_bits(a.x); v[1] = f32_to_bf16_bits(a.y);
        v[2] = f32_to_bf16_bits(a.z); v[3] = f32_to_bf16_bits(a.w);
        v[4] = f32_to_bf16_bits(b.x); v[5] = f32_to_bf16_bits(b.y);
        v[6] = f32_to_bf16_bits(b.z); v[7] = f32_to_bf16_bits(b.w);
        yb[(size_t)row * YSLOTS + o] = v;
    }
#pragma unroll
    for (int off = 32; off > 0; off >>= 1)
        ss += __shfl_down(ss, off, 64);
    if (lane == 0) {
        if (wid < 2) part[wid] = ss;
        else         sqy[row] = ss;
    }
    __syncthreads();
    if (t == 0) sqx[row] = part[0] + part[1];
}

// ===========================================================================
// FAST PATH: 64^2 tiles
// ===========================================================================

// Stage combined A|B tile: [128 rows][8 slots], rows 0-63 = A rows iA..iA+63,
// rows 64-127 = B rows iB..iB+63; slots k0..k0+7 (BK=64). LDS dest LINEAR;
// XOR swizzle lives in the per-lane GLOBAL source (rule #21): stored slot st
// of row r holds logical slot st ^ (r & 7). 4 global_load_lds per wave.
__device__ __forceinline__ void stage64(const u16x8* __restrict__ src, int rowslots,
                                        int iA, int iB, int k0,
                                        u16x8* dst, int tid) {
    const int wid = tid >> 6, lane = tid & 63;
#pragma unroll
    for (int it = 0; it < 4; ++it) {
        int u   = it * 256 + wid * 64;   // wave-uniform LDS slot base
        int ul  = u + lane;
        int row = ul >> 3;               // 0..127
        int st  = ul & 7;
        int lg  = st ^ (row & 7);
        int grow = (row < 64 ? iA + row : iB + row - 64);
        const u16x8* g = src + (size_t)grow * rowslots + k0 + lg;
        __builtin_amdgcn_global_load_lds(
            (const uint32_t __attribute__((address_space(1)))*)g,
            (uint32_t __attribute__((address_space(3)))*)(dst + u), 16, 0, 0);
    }
}

// One BK=64 step: 2 ks x (2x2) MFMA; wave tile 32x32 at (wr*32, wc*32).
__device__ __forceinline__ void step64(const u16x8* T, int wr, int wc,
                                       int lrow, int kgrp, f32x4 acc[2][2]) {
#pragma unroll
    for (int ks = 0; ks < 2; ++ks) {
        bf16x8 a[2], b[2];
#pragma unroll
        for (int m = 0; m < 2; ++m) {
            int row = wr * 32 + m * 16 + lrow;
            int st  = (ks * 4 + kgrp) ^ (row & 7);
            a[m] = __builtin_bit_cast(bf16x8, T[row * 8 + st]);
        }
#pragma unroll
        for (int n = 0; n < 2; ++n) {
            int row = 64 + wc * 32 + n * 16 + lrow;
            int st  = (ks * 4 + kgrp) ^ (row & 7);
            b[n] = __builtin_bit_cast(bf16x8, T[row * 8 + st]);
        }
#pragma unroll
        for (int m = 0; m < 2; ++m)
#pragma unroll
            for (int n = 0; n < 2; ++n)
                acc[m][n] = __builtin_amdgcn_mfma_f32_16x16x32_bf16(
                    a[m], b[n], acc[m][n], 0, 0, 0);
    }
}

__global__ void __launch_bounds__(256, 4)
graph_loss_bf16(const u16x8* __restrict__ xb, const u16x8* __restrict__ yb,
                const float* __restrict__ sqx, const float* __restrict__ sqy,
                float* __restrict__ out) {
    __shared__ u16x8 T[1024];            // 16 KB combined A|B tile
    __shared__ float snxA[BM2], snxB[BM2], snyA[BM2], snyB[BM2];
    __shared__ float wsum[4];

    const int tid  = threadIdx.x;
    const int lane = tid & 63;
    const int wid  = tid >> 6;
    const int wr   = wid >> 1;
    const int wc   = wid & 1;
    const int lrow = lane & 15;
    const int kgrp = lane >> 4;

    // T1: chunked XCD swizzle (bijective: NBLK2 % 8 == 0).
    int sb = (blockIdx.x & 7) * (NBLK2 / 8) + (blockIdx.x >> 3);

    // triangular tile mapping
    int t0 = sb, bi = 0;
    while (t0 >= NT2 - bi) { t0 -= NT2 - bi; ++bi; }
    const int bj = bi + t0;
    const int iA = bi * BM2;
    const int iB = bj * BM2;
    const bool diag = (bi == bj);

    if (tid < BM2) {
        snxA[tid] = sqx[iA + tid];
        snyA[tid] = sqy[iA + tid];
        snxB[tid] = sqx[iB + tid];
        snyB[tid] = sqy[iB + tid];
    }

    f32x4 accX[2][2] = {};
    f32x4 accY[2][2] = {};

    // ---- X phase: 16 steps of BK=64 (2-barrier structure; co-resident
    //      blocks provide the latency hiding -- m114) ----
    for (int t = 0; t < NS2X; ++t) {
        __syncthreads();
        stage64(xb, XSLOTS, iA, iB, t * 8, T, tid);
        __syncthreads();
        step64(T, wr, wc, lrow, kgrp, accX);
    }
    // ---- Y phase: 8 steps ----
    for (int t = 0; t < NS2Y; ++t) {
        __syncthreads();
        stage64(yb, YSLOTS, iA, iB, t * 8, T, tid);
        __syncthreads();
        step64(T, wr, wc, lrow, kgrp, accY);
    }

    // ---- Epilogue: C/D layout col=lane&15, row=(lane>>4)*4+reg (m89) ----
    float local = 0.f;
#pragma unroll
    for (int m = 0; m < 2; ++m) {
#pragma unroll
        for (int n = 0; n < 2; ++n) {
            int col   = wc * 32 + n * 16 + lrow;
            float sxj = snxB[col];
            float syj = snyB[col];
#pragma unroll
            for (int r = 0; r < 4; ++r) {
                int rowi  = wr * 32 + m * 16 + kgrp * 4 + r;
                float d2x = snxA[rowi] + sxj - 2.f * accX[m][n][r];
                float dxv = sqrtf(fmaxf(d2x, 1e-12f));
                float d2y = snyA[rowi] + syj - 2.f * accY[m][n][r];
                float dyv = sqrtf(fmaxf(d2y, 1e-12f));
                int gi = iA + rowi, gj = iB + col;
                bool keep = (gi != gj) && (dxv <= EPS_THR);
                float contrib = __expf(-dxv * SIGMA_INV) * dyv;
                local += keep ? contrib : 0.f;
            }
        }
    }
    if (!diag) local *= 2.f;

#pragma unroll
    for (int off = 32; off > 0; off >>= 1)
        local += __shfl_down(local, off, 64);
    if (lane == 0) wsum[wid] = local;
    __syncthreads();
    if (tid == 0)
        atomicAdd(out, wsum[0] + wsum[1] + wsum[2] + wsum[3]);
}

// ===========================================================================
// FALLBACK PATH (used only if ws_size is too small) — round-2 structure.
// ===========================================================================
__global__ void norms_kernel_fb(const float* __restrict__ x,
                                const float* __restrict__ y,
                                float* __restrict__ sqx,
                                float* __restrict__ sqy) {
    int row = blockIdx.x;
    int t   = threadIdx.x;
    const float4* xr = (const float4*)(x + (size_t)row * D_X);
    float sx = 0.f;
#pragma unroll
    for (int i = 0; i < D_X / 4 / 64; ++i) {
        float4 v = xr[t + i * 64];
        sx += v.x * v.x + v.y * v.y + v.z * v.z + v.w * v.w;
    }
    const float4* yr = (const float4*)(y + (size_t)row * D_Y);
    float sy = 0.f;
#pragma unroll
    for (int i = 0; i < D_Y / 4 / 64; ++i) {
        float4 v = yr[t + i * 64];
        sy += v.x * v.x + v.y * v.y + v.z * v.z + v.w * v.w;
    }
#pragma unroll
    for (int off = 32; off > 0; off >>= 1) {
        sx += __shfl_down(sx, off, 64);
        sy += __shfl_down(sy, off, 64);
    }
    if (t == 0) { sqx[row] = sx; sqy[row] = sy; }
}

__device__ __forceinline__ void stage_tile_fb(const float* __restrict__ src, int ld,
                                              int base_row, int k0,
                                              u16x8* __restrict__ dst, int tid) {
#pragma unroll
    for (int it = 0; it < 2; ++it) {
        int u   = tid + it * 256;
        int row = u >> 2;
        int q   = u & 3;
        const float4* p = (const float4*)(src + (size_t)(base_row + row) * ld + k0 + q * 16);
        float4 f0 = p[0], f1 = p[1], f2 = p[2], f3 = p[3];
        u16x8 lo, hi;
        lo[0] = f32_to_bf16_bits(f0.x); lo[1] = f32_to_bf16_bits(f0.y);
        lo[2] = f32_to_bf16_bits(f0.z); lo[3] = f32_to_bf16_bits(f0.w);
        lo[4] = f32_to_bf16_bits(f1.x); lo[5] = f32_to_bf16_bits(f1.y);
        lo[6] = f32_to_bf16_bits(f1.z); lo[7] = f32_to_bf16_bits(f1.w);
        hi[0] = f32_to_bf16_bits(f2.x); hi[1] = f32_to_bf16_bits(f2.y);
        hi[2] = f32_to_bf16_bits(f2.z); hi[3] = f32_to_bf16_bits(f2.w);
        hi[4] = f32_to_bf16_bits(f3.x); hi[5] = f32_to_bf16_bits(f3.y);
        hi[6] = f32_to_bf16_bits(f3.z); hi[7] = f32_to_bf16_bits(f3.w);
        int swz = row & 7;
        dst[row * 8 + ((2 * q) ^ swz)]     = lo;
        dst[row * 8 + ((2 * q + 1) ^ swz)] = hi;
    }
}

__device__ __forceinline__ void mfma16_fb(const bf16x8 a[4], const bf16x8 b[4],
                                          f32x4 acc[4][4]) {
#pragma unroll
    for (int m = 0; m < 4; ++m)
#pragma unroll
        for (int n = 0; n < 4; ++n)
            acc[m][n] = __builtin_amdgcn_mfma_f32_16x16x32_bf16(
                a[m], b[n], acc[m][n], 0, 0, 0);
}

__device__ __forceinline__ void load_frags_fb(const u16x8* As_, const u16x8* Bs_,
                                              int wr, int wc, int lrow, int kgrp,
                                              bf16x8 a[2][4], bf16x8 b[2][4]) {
#pragma unroll
    for (int ks = 0; ks < 2; ++ks) {
#pragma unroll
        for (int m = 0; m < 4; ++m) {
            int row  = wr * 64 + m * 16 + lrow;
            int slot = (ks * 4 + kgrp) ^ (row & 7);
            a[ks][m] = __builtin_bit_cast(bf16x8, As_[row * 8 + slot]);
        }
#pragma unroll
        for (int n = 0; n < 4; ++n) {
            int row  = wc * 64 + n * 16 + lrow;
            int slot = (ks * 4 + kgrp) ^ (row & 7);
            b[ks][n] = __builtin_bit_cast(bf16x8, Bs_[row * 8 + slot]);
        }
    }
}

__global__ void __launch_bounds__(256, 2)
graph_loss_fb(const float* __restrict__ x, const float* __restrict__ y,
              const float* __restrict__ sqx, const float* __restrict__ sqy,
              float* __restrict__ out) {
    __shared__ u16x8 As[BM * 8];
    __shared__ u16x8 Bs[BM * 8];
    __shared__ float snxA[BM], snxB[BM], snyA[BM], snyB[BM];
    __shared__ float wsum[4];

    const int tid  = threadIdx.x;
    const int lane = tid & 63;
    const int wid  = tid >> 6;
    const int wr   = wid >> 1;
    const int wc   = wid & 1;
    const int lrow = lane & 15;
    const int kgrp = lane >> 4;

    int t = blockIdx.x, bi = 0;
    while (t >= NT - bi) { t -= NT - bi; ++bi; }
    const int bj = bi + t;
    const int iA = bi * BM;
    const int iB = bj * BM;

    if (tid < BM) {
        snxA[tid] = sqx[iA + tid];
        snyA[tid] = sqy[iA + tid];
        snxB[tid] = sqx[iB + tid];
        snyB[tid] = sqy[iB + tid];
    }

    f32x4 accX[4][4] = {};
    f32x4 accY[4][4] = {};
    bf16x8 a[2][4], b[2][4];

    for (int kt = 0; kt < D_X / 64; ++kt) {
        __syncthreads();
        stage_tile_fb(x, D_X, iA, kt * 64, As, tid);
        stage_tile_fb(x, D_X, iB, kt * 64, Bs, tid);
        __syncthreads();
        load_frags_fb(As, Bs, wr, wc, lrow, kgrp, a, b);
#pragma unroll
        for (int ks = 0; ks < 2; ++ks) mfma16_fb(a[ks], b[ks], accX);
    }
    for (int kt = 0; kt < D_Y / 64; ++kt) {
        __syncthreads();
        stage_tile_fb(y, D_Y, iA, kt * 64, As, tid);
        stage_tile_fb(y, D_Y, iB, kt * 64, Bs, tid);
        __syncthreads();
        load_frags_fb(As, Bs, wr, wc, lrow, kgrp, a, b);
#pragma unroll
        for (int ks = 0; ks < 2; ++ks) mfma16_fb(a[ks], b[ks], accY);
    }

    float local = 0.f;
#pragma unroll
    for (int m = 0; m < 4; ++m) {
#pragma unroll
        for (int n = 0; n < 4; ++n) {
            int col   = wc * 64 + n * 16 + lrow;
            float sxj = snxB[col];
            float syj = snyB[col];
#pragma unroll
            for (int r = 0; r < 4; ++r) {
                int rowi  = wr * 64 + m * 16 + kgrp * 4 + r;
                float d2x = snxA[rowi] + sxj - 2.f * accX[m][n][r];
                float dxv = sqrtf(fmaxf(d2x, 1e-12f));
                float d2y = snyA[rowi] + syj - 2.f * accY[m][n][r];
                float dyv = sqrtf(fmaxf(d2y, 1e-12f));
                int gi = iA + rowi, gj = iB + col;
                bool keep = (gi != gj) && (dxv <= EPS_THR);
                float contrib = __expf(-dxv * SIGMA_INV) * dyv;
                local += keep ? contrib : 0.f;
            }
        }
    }
    if (bi != bj) local *= 2.f;

#pragma unroll
    for (int off = 32; off > 0; off >>= 1)
        local += __shfl_down(local, off, 64);
    if (lane == 0) wsum[wid] = local;
    __syncthreads();
    if (tid == 0)
        atomicAdd(out, wsum[0] + wsum[1] + wsum[2] + wsum[3]);
}

// ===========================================================================
extern "C" void kernel_launch(void* const* d_in, const int* in_sizes, int n_in,
                              void* d_out, int out_size, void* d_ws, size_t ws_size,
                              hipStream_t stream) {
    const float* x = (const float*)d_in[0];
    const float* y = (const float*)d_in[1];
    float* out = (float*)d_out;

    hipMemsetAsync(d_out, 0, sizeof(float) * (size_t)out_size, stream);

    const size_t xb_bytes = (size_t)BATCH * XSLOTS * 16;   // 8 MB
    const size_t yb_bytes = (size_t)BATCH * YSLOTS * 16;   // 4 MB
    const size_t need = xb_bytes + yb_bytes + 2 * (size_t)BATCH * sizeof(float);

    if (ws_size >= need) {
        u16x8* xb  = (u16x8*)d_ws;
        u16x8* yb  = (u16x8*)((char*)d_ws + xb_bytes);
        float* sqx = (float*)((char*)d_ws + xb_bytes + yb_bytes);
        float* sqy = sqx + BATCH;
        convert_kernel<<<BATCH, 192, 0, stream>>>(x, y, xb, yb, sqx, sqy);
        graph_loss_bf16<<<NBLK2, 256, 0, stream>>>(xb, yb, sqx, sqy, out);
    } else {
        float* sqx = (float*)d_ws;
        float* sqy = sqx + BATCH;
        norms_kernel_fb<<<BATCH, 64, 0, stream>>>(x, y, sqx, sqy);
        graph_loss_fb<<<NBLK, 256, 0, stream>>>(x, y, sqx, sqy, out);
    }
}